// Round 8
// baseline (88.568 us; speedup 1.0000x reference)
//
#include <hip/hip_runtime.h>
#include <math.h>

#define N      4096
#define BLOCK  64                  // ONE wave per block
#define IT     64                  // i-tile height
#define JW     32                  // j-tile width
#define NQ     (JW / 4)            // 8 PAIR4 groups
// upper-tri tiles: itile t has (4096-64t)/32 = 128-2t j-segments;
// off(t) = t*(129-t); total = off(64) = 4160 per batch
#define NTRI   4160

typedef float v4f __attribute__((ext_vector_type(4)));

// s(e) = sum_k 1/(1 + c_k*e), c_k = e^{-t_k}, t = {0.5,1,2,4} = Pn(e)/Pd(e)
#define PN0 4.0f
#define PN1 3.384183069f
#define PN2 0.750655861f
#define PN3 0.036699475f
#define PD1 1.128061023f
#define PD2 0.375327930f
#define PD3 0.036699475f
#define PD4 0.000553084f

__device__ __forceinline__ v4f splat(float x) { return (v4f){x, x, x, x}; }

// NOTE (R4/R5): no fused atomic+fence+ticket finalize (serialized wave-0s,
// +55 us). NOTE (R7): v_pk_* f32 is issue-neutral on CDNA4 (157 TF peak
// already = plain v_fma_f32 rate) - don't chase packed math.
// NOTE (R8): single-wave blocks: 8320 waves / 8192 wave-slots = 1.016
// rounds, no real barriers, pure-shuffle epilogue.
__global__ __launch_bounds__(BLOCK, 4) void lddt_main_kernel(
    const float* __restrict__ pred, const float* __restrict__ truec,
    const int* __restrict__ is_dna, const int* __restrict__ is_rna,
    const int* __restrict__ cmask, float* __restrict__ ws)
{
    const int L     = blockIdx.x;     // 0..NTRI-1
    const int batch = blockIdx.z;
    const int tid   = threadIdx.x;    // 0..63

    // decode itile t from L: off(t) = t*(129-t) <= L < off(t+1)
    int t = (int)((129.0f - __builtin_amdgcn_sqrtf((float)(16641 - 4 * L))) * 0.5f);
    t = (t > 63) ? 63 : ((t < 0) ? 0 : t);
    while (t * (129 - t) > L) --t;                 // fp rounding fixups
    while ((t + 1) * (128 - t) <= L) ++t;
    const int jloc = L - t * (129 - t);
    const int j0   = 64 * t + 32 * jloc;
    const bool diag = (jloc < 2);                  // j-range overlaps i-range

    const int i = 64 * t + tid;

    const float* pb = pred  + (size_t)batch * N * 3;
    const float* tb = truec + (size_t)batch * N * 3;
    const int* dnab = is_dna + (size_t)batch * N;
    const int* rnab = is_rna + (size_t)batch * N;
    const int* cmb  = cmask  + (size_t)batch * N;

    // SoA j-tile staging; all inner-loop reads are wave-uniform broadcasts.
    __shared__ v4f spx[NQ], spy[NQ], spz[NQ], snw[NQ];
    __shared__ v4f stx[NQ], sty[NQ], stz[NQ], scw[NQ];
    if (tid < JW) {                                // lanes 0-31: pred + nuc
        const int j = j0 + tid;
        ((float*)spx)[tid] = pb[j*3+0];
        ((float*)spy)[tid] = pb[j*3+1];
        ((float*)spz)[tid] = pb[j*3+2];
        ((float*)snw)[tid] = (dnab[j] | rnab[j]) ? 675.0f : 0.0f;  // 30^2-15^2
    } else {                                       // lanes 32-63: true + cm
        const int j = j0 + tid - JW;
        ((float*)stx)[tid - JW] = tb[j*3+0];
        ((float*)sty)[tid - JW] = tb[j*3+1];
        ((float*)stz)[tid - JW] = tb[j*3+2];
        ((float*)scw)[tid - JW] = cmb[j] ? 1.0f : 0.0f;
    }
    __syncthreads();   // single wave: compiles to a waitcnt-grade barrier

    const float pix = pb[i*3+0], piy = pb[i*3+1], piz = pb[i*3+2];
    const float tix = tb[i*3+0], tiy = tb[i*3+1], tiz = tb[i*3+2];
    const float inuc01 = (dnab[i] | rnab[i]) ? 1.0f : 0.0f;
    const float icm    = cmb[i] ? 1.0f : 0.0f;

    const v4f pix4 = splat(pix), piy4 = splat(piy), piz4 = splat(piz);
    const v4f tix4 = splat(tix), tiy4 = splat(tiy), tiz4 = splat(tiz);
    const v4f base = splat(225.0f);          // 15^2
    const v4f inuc4 = splat(inuc01);

    float num = 0.0f;
    v4f den4 = splat(0.0f);

    // 4 pairs per group; ONE shared rcp per group:
    // sum t_k/d_k = [(t1 d2 + t2 d1) d34 + (t3 d4 + t4 d3) d12] * rcp(d12*d34)
    // dd clamped to 5 so d12*d34 <= ~2.5e22 (no overflow); bias <= 5e-4.
#define PAIR4(Q, NEED_TRI)                                                     \
    {                                                                          \
        const v4f Px = spx[Q], Py = spy[Q], Pz = spz[Q], Pw = snw[Q];          \
        const v4f Tx = stx[Q], Ty = sty[Q], Tz = stz[Q], Tw = scw[Q];          \
        v4f dxp = pix4 - Px, dyp = piy4 - Py, dzp = piz4 - Pz;                 \
        v4f d2p = dxp * dxp + dyp * dyp + dzp * dzp;                           \
        v4f dxt = tix4 - Tx, dyt = tiy4 - Ty, dzt = tiz4 - Tz;                 \
        v4f d2t = dxt * dxt + dyt * dyt + dzt * dzt;                           \
        v4f dp, dt;                                                            \
        dp.x = __builtin_amdgcn_sqrtf(d2p.x); dt.x = __builtin_amdgcn_sqrtf(d2t.x); \
        dp.y = __builtin_amdgcn_sqrtf(d2p.y); dt.y = __builtin_amdgcn_sqrtf(d2t.y); \
        dp.z = __builtin_amdgcn_sqrtf(d2p.z); dt.z = __builtin_amdgcn_sqrtf(d2t.z); \
        dp.w = __builtin_amdgcn_sqrtf(d2p.w); dt.w = __builtin_amdgcn_sqrtf(d2t.w); \
        v4f dd = dt - dp;                                                      \
        v4f e;                                                                 \
        e.x = __expf(fminf(fabsf(dd.x), 5.0f));                                \
        e.y = __expf(fminf(fabsf(dd.y), 5.0f));                                \
        e.z = __expf(fminf(fabsf(dd.z), 5.0f));                                \
        e.w = __expf(fminf(fabsf(dd.w), 5.0f));                                \
        v4f NN = ((e * splat(PN3) + splat(PN2)) * e + splat(PN1)) * e + splat(PN0); \
        v4f ND = (((e * splat(PD4) + splat(PD3)) * e + splat(PD2)) * e + splat(PD1)) * e + splat(1.0f); \
        v4f cut = base + inuc4 * Pw;                                           \
        v4f m;                                                                 \
        { bool k0 = d2t.x < cut.x, k1 = d2t.y < cut.y,                         \
           k2 = d2t.z < cut.z, k3 = d2t.w < cut.w;                             \
          if (NEED_TRI) { const int jb = j0 + 4 * (Q);                         \
            k0 = k0 && (jb + 0 > i); k1 = k1 && (jb + 1 > i);                  \
            k2 = k2 && (jb + 2 > i); k3 = k3 && (jb + 3 > i); }                \
          m.x = k0 ? Tw.x : 0.0f; m.y = k1 ? Tw.y : 0.0f;                      \
          m.z = k2 ? Tw.z : 0.0f; m.w = k3 ? Tw.w : 0.0f; }                    \
        v4f tt = m * NN;                                                       \
        den4 += m;                                                             \
        float d12 = ND.x * ND.y, d34 = ND.z * ND.w;                            \
        float a = fmaf(tt.x, ND.y, tt.y * ND.x);                               \
        float c = fmaf(tt.z, ND.w, tt.w * ND.z);                               \
        float nr = fmaf(a, d34, c * d12);                                      \
        num = fmaf(nr, __builtin_amdgcn_rcpf(d12 * d34), num);                 \
    }

    if (diag) {
#pragma unroll 2
        for (int q = 0; q < NQ; ++q) PAIR4(q, true)
    } else {
#pragma unroll 2
        for (int q = 0; q < NQ; ++q) PAIR4(q, false)
    }
#undef PAIR4

    float den = den4.x + den4.y + den4.z + den4.w;

    // symmetry x2, threshold-mean /4, gate by cm_i
    num *= 0.5f * icm;
    den *= 2.0f * icm;

    // single-wave shuffle reduction, no LDS step
    for (int off = 32; off > 0; off >>= 1) {
        num += __shfl_down(num, off);
        den += __shfl_down(den, off);
    }
    if (tid == 0) {
        const int bid = batch * NTRI + L;
        ws[bid * 2 + 0] = num;   // plain stores to distinct slots
        ws[bid * 2 + 1] = den;
    }
}

__global__ __launch_bounds__(256) void finalize_kernel(
    const float* __restrict__ ws, float* __restrict__ out, int b)
{
    __shared__ float sn[4], sd[4];
    float acc = 0.0f;
    for (int k = 0; k < b; ++k) {
        float n = 0.0f, d = 0.0f;
        for (int p = threadIdx.x; p < NTRI; p += 256) {
            n += ws[(k * NTRI + p) * 2 + 0];
            d += ws[(k * NTRI + p) * 2 + 1];
        }
        for (int off = 32; off > 0; off >>= 1) {
            n += __shfl_down(n, off);
            d += __shfl_down(d, off);
        }
        if ((threadIdx.x & 63) == 0) { sn[threadIdx.x >> 6] = n; sd[threadIdx.x >> 6] = d; }
        __syncthreads();
        if (threadIdx.x == 0) {
            float tn = sn[0] + sn[1] + sn[2] + sn[3];
            float td = sd[0] + sd[1] + sd[2] + sd[3];
            acc += tn / fmaxf(td, 1.0f);
        }
        __syncthreads();
    }
    if (threadIdx.x == 0) out[0] = 1.0f - acc / (float)b;
}

extern "C" void kernel_launch(void* const* d_in, const int* in_sizes, int n_in,
                              void* d_out, int out_size, void* d_ws, size_t ws_size,
                              hipStream_t stream) {
    const float* pred  = (const float*)d_in[0];
    const float* truec = (const float*)d_in[1];
    const int* is_dna  = (const int*)d_in[2];
    const int* is_rna  = (const int*)d_in[3];
    const int* cmask   = (const int*)d_in[4];
    float* out = (float*)d_out;
    float* ws  = (float*)d_ws;

    const int b = in_sizes[2] / N;

    dim3 grid(NTRI, 1, b);   // 4160 x b one-wave blocks = 8320 waves (b=2)
    lddt_main_kernel<<<grid, BLOCK, 0, stream>>>(pred, truec, is_dna, is_rna, cmask, ws);
    finalize_kernel<<<1, 256, 0, stream>>>(ws, out, b);
}

// Round 10
// 85.107 us; speedup vs baseline: 1.0407x; 1.0407x over previous
//
#include <hip/hip_runtime.h>
#include <math.h>

#define N      4096
#define BLOCK  256
#define JW     32                  // j-tile width
#define NITILE (N / BLOCK)         // 16 i-tiles (256 rows each)
#define NTRI   1088                // sum_{t=0..15} (128 - 8t)
#define NQ     (JW / 4)            // 8 PAIR4 groups

typedef float v4f __attribute__((ext_vector_type(4)));
typedef _Float16 h2  __attribute__((ext_vector_type(2)));
typedef _Float16 v8h __attribute__((ext_vector_type(8)));

// Coordinates pre-scaled by L = log2(e) so e^dd == exp2(dd_scaled).
#define LOG2E   1.4426950408889634f
#define BASE_SQ 468.30802f          // 225 * L^2   (15^2, scaled-d2 domain)
#define NUC_SQ  1404.92406f         // 675 * L^2   (30^2-15^2, scaled)
#define CLAMP_S 7.2134752f          // 5 * L  (dd clamp in scaled units)
#define TPOISON ((_Float16)30000.0f) // masked-j true-coord poison -> d2t=inf

// s(e) = sum_k 1/(1 + c_k*e), c_k = e^{-t_k}, t = {0.5,1,2,4} = Pn(e)/Pd(e)
#define PN0 4.0f
#define PN1 3.384183069f
#define PN2 0.750655861f
#define PN3 0.036699475f
#define PD1 1.128061023f
#define PD2 0.375327930f
#define PD3 0.036699475f
#define PD4 0.000553084f

__device__ __forceinline__ int tri_off(int t) { return 132 * t - 4 * t * t; }
__device__ __forceinline__ v4f splat(float x) { return (v4f){x, x, x, x}; }

// R4/R5: no fused atomic+fence+ticket finalize (2176 serialized wave-0s,
// +55 us). R4: launch_bounds (256,8) -> 32-VGPR cap -> loop spills, 3x slow.
// R7: v_pk_fma_f32 is issue-neutral on CDNA4 (157 TF = plain FMA rate).
// R8: 1-wave blocks regress: 4x blocks -> 4x prologue, amortization loss.
// R9: fp16 v_pk_* DOES halve issue (2 halves/instr); p/t packed per lane.
//     NOTE: __exp2f does not exist device-side (glibc macro clash) -> use
//     __builtin_amdgcn_exp2f (raw v_exp_f32, which is natively exp2).
__global__ __launch_bounds__(BLOCK, 4) void lddt_main_kernel(
    const float* __restrict__ pred, const float* __restrict__ truec,
    const int* __restrict__ is_dna, const int* __restrict__ is_rna,
    const int* __restrict__ cmask, float* __restrict__ ws)
{
    const int L     = blockIdx.x;     // 0..NTRI-1, linear upper-tri tile id
    const int batch = blockIdx.z;
    const int tid   = threadIdx.x;

    int itile = 0;
#pragma unroll
    for (int u = 1; u < NITILE; ++u) itile += (L >= tri_off(u)) ? 1 : 0;
    const int jseg = 8 * itile + (L - tri_off(itile));
    const bool diag = (jseg < 8 * itile + 8);   // j-range overlaps i-range

    const int i = itile * BLOCK + tid;

    const float* pb = pred  + (size_t)batch * N * 3;
    const float* tb = truec + (size_t)batch * N * 3;
    const int* dnab = is_dna + (size_t)batch * N;
    const int* rnab = is_rna + (size_t)batch * N;
    const int* cmb  = cmask  + (size_t)batch * N;

    // SoA j-tile: 3 fp16-packed coord channels (lo=pred_s, hi=true_s) + nuc.
    // cm_j folded in by poisoning true coords of masked j (d2t=inf -> m=0).
    __shared__ v8h sx[NQ], sy[NQ], sz[NQ];
    __shared__ v4f snw[NQ];
    const int j0 = jseg * JW;
    if (tid < JW) {
        const int j = j0 + tid;
        const bool jc = cmb[j] != 0;
        h2 cx, cy, cz;
        cx[0] = (_Float16)(pb[j*3+0] * LOG2E);
        cy[0] = (_Float16)(pb[j*3+1] * LOG2E);
        cz[0] = (_Float16)(pb[j*3+2] * LOG2E);
        cx[1] = jc ? (_Float16)(tb[j*3+0] * LOG2E) : TPOISON;
        cy[1] = jc ? (_Float16)(tb[j*3+1] * LOG2E) : TPOISON;
        cz[1] = jc ? (_Float16)(tb[j*3+2] * LOG2E) : TPOISON;
        ((h2*)sx)[tid] = cx;
        ((h2*)sy)[tid] = cy;
        ((h2*)sz)[tid] = cz;
    } else if (tid < 2 * JW) {
        const int j = j0 + tid - JW;
        ((float*)snw)[tid - JW] = (dnab[j] | rnab[j]) ? NUC_SQ : 0.0f;
    }
    __syncthreads();

    const float pix = pb[i*3+0] * LOG2E, piy = pb[i*3+1] * LOG2E, piz = pb[i*3+2] * LOG2E;
    const float tix = tb[i*3+0] * LOG2E, tiy = tb[i*3+1] * LOG2E, tiz = tb[i*3+2] * LOG2E;
    const float inuc01 = (dnab[i] | rnab[i]) ? 1.0f : 0.0f;
    const float icm    = cmb[i] ? 1.0f : 0.0f;

    // i-row packed splats {p,t, p,t, ...}
    const h2 ix2 = {(_Float16)pix, (_Float16)tix};
    const h2 iy2 = {(_Float16)piy, (_Float16)tiy};
    const h2 iz2 = {(_Float16)piz, (_Float16)tiz};
    const v8h ix8 = {ix2[0], ix2[1], ix2[0], ix2[1], ix2[0], ix2[1], ix2[0], ix2[1]};
    const v8h iy8 = {iy2[0], iy2[1], iy2[0], iy2[1], iy2[0], iy2[1], iy2[0], iy2[1]};
    const v8h iz8 = {iz2[0], iz2[1], iz2[0], iz2[1], iz2[0], iz2[1], iz2[0], iz2[1]};

    const v4f base  = splat(BASE_SQ);
    const v4f inuc4 = splat(inuc01);

    float num = 0.0f;
    v4f den4 = splat(0.0f);

    // 4 pairs per group; packed fp16 distance math; ONE rcp per group.
#define PAIR4(Q, NEED_TRI)                                                     \
    {                                                                          \
        v8h dx = ix8 - sx[Q], dy = iy8 - sy[Q], dz = iz8 - sz[Q];              \
        v8h d2 = dx * dx + dy * dy + dz * dz;   /* lo=pred, hi=true, x4 j */   \
        v4f d2p4 = {(float)d2[0], (float)d2[2], (float)d2[4], (float)d2[6]};   \
        v4f d2t4 = {(float)d2[1], (float)d2[3], (float)d2[5], (float)d2[7]};   \
        v4f dp, dt;                                                            \
        dp.x = __builtin_amdgcn_sqrtf(d2p4.x); dt.x = __builtin_amdgcn_sqrtf(d2t4.x); \
        dp.y = __builtin_amdgcn_sqrtf(d2p4.y); dt.y = __builtin_amdgcn_sqrtf(d2t4.y); \
        dp.z = __builtin_amdgcn_sqrtf(d2p4.z); dt.z = __builtin_amdgcn_sqrtf(d2t4.z); \
        dp.w = __builtin_amdgcn_sqrtf(d2p4.w); dt.w = __builtin_amdgcn_sqrtf(d2t4.w); \
        v4f dd = dt - dp;                                                      \
        v4f e;  /* e^|dd| == exp2(|dd_scaled|), clamped */                     \
        e.x = __builtin_amdgcn_exp2f(fminf(fabsf(dd.x), CLAMP_S));             \
        e.y = __builtin_amdgcn_exp2f(fminf(fabsf(dd.y), CLAMP_S));             \
        e.z = __builtin_amdgcn_exp2f(fminf(fabsf(dd.z), CLAMP_S));             \
        e.w = __builtin_amdgcn_exp2f(fminf(fabsf(dd.w), CLAMP_S));             \
        v4f NN = ((e * splat(PN3) + splat(PN2)) * e + splat(PN1)) * e + splat(PN0); \
        v4f ND = (((e * splat(PD4) + splat(PD3)) * e + splat(PD2)) * e + splat(PD1)) * e + splat(1.0f); \
        v4f cut = base + inuc4 * snw[Q];                                       \
        v4f m;                                                                 \
        { bool k0 = d2t4.x < cut.x, k1 = d2t4.y < cut.y,                       \
           k2 = d2t4.z < cut.z, k3 = d2t4.w < cut.w;                           \
          if (NEED_TRI) { const int jb = j0 + 4 * (Q);                         \
            k0 = k0 && (jb + 0 > i); k1 = k1 && (jb + 1 > i);                  \
            k2 = k2 && (jb + 2 > i); k3 = k3 && (jb + 3 > i); }                \
          m.x = k0 ? 1.0f : 0.0f; m.y = k1 ? 1.0f : 0.0f;                      \
          m.z = k2 ? 1.0f : 0.0f; m.w = k3 ? 1.0f : 0.0f; }                    \
        v4f tt = m * NN;                                                       \
        den4 += m;                                                             \
        float d12 = ND.x * ND.y, d34 = ND.z * ND.w;                            \
        float a = fmaf(tt.x, ND.y, tt.y * ND.x);                               \
        float c = fmaf(tt.z, ND.w, tt.w * ND.z);                               \
        float nr = fmaf(a, d34, c * d12);                                      \
        num = fmaf(nr, __builtin_amdgcn_rcpf(d12 * d34), num);                 \
    }

    if (diag) {
#pragma unroll 2
        for (int q = 0; q < NQ; ++q) PAIR4(q, true)
    } else {
#pragma unroll 2
        for (int q = 0; q < NQ; ++q) PAIR4(q, false)
    }
#undef PAIR4

    float den = den4.x + den4.y + den4.z + den4.w;

    // symmetry x2, threshold-mean /4, gate by cm_i
    num *= 0.5f * icm;
    den *= 2.0f * icm;

    for (int off = 32; off > 0; off >>= 1) {
        num += __shfl_down(num, off);
        den += __shfl_down(den, off);
    }
    __shared__ float rn[BLOCK / 64], rd[BLOCK / 64];
    const int wid = tid >> 6, lane = tid & 63;
    if (lane == 0) { rn[wid] = num; rd[wid] = den; }
    __syncthreads();
    if (tid == 0) {
        float tn = rn[0] + rn[1] + rn[2] + rn[3];
        float td = rd[0] + rd[1] + rd[2] + rd[3];
        const int bid = batch * NTRI + L;
        ws[bid * 2 + 0] = tn;   // plain stores to distinct slots
        ws[bid * 2 + 1] = td;
    }
}

__global__ __launch_bounds__(BLOCK) void finalize_kernel(
    const float* __restrict__ ws, float* __restrict__ out, int b)
{
    __shared__ float sn[4], sd[4];
    float acc = 0.0f;
    for (int k = 0; k < b; ++k) {
        float n = 0.0f, d = 0.0f;
        for (int p = threadIdx.x; p < NTRI; p += BLOCK) {
            n += ws[(k * NTRI + p) * 2 + 0];
            d += ws[(k * NTRI + p) * 2 + 1];
        }
        for (int off = 32; off > 0; off >>= 1) {
            n += __shfl_down(n, off);
            d += __shfl_down(d, off);
        }
        if ((threadIdx.x & 63) == 0) { sn[threadIdx.x >> 6] = n; sd[threadIdx.x >> 6] = d; }
        __syncthreads();
        if (threadIdx.x == 0) {
            float tn = sn[0] + sn[1] + sn[2] + sn[3];
            float td = sd[0] + sd[1] + sd[2] + sd[3];
            acc += tn / fmaxf(td, 1.0f);
        }
        __syncthreads();
    }
    if (threadIdx.x == 0) out[0] = 1.0f - acc / (float)b;
}

extern "C" void kernel_launch(void* const* d_in, const int* in_sizes, int n_in,
                              void* d_out, int out_size, void* d_ws, size_t ws_size,
                              hipStream_t stream) {
    const float* pred  = (const float*)d_in[0];
    const float* truec = (const float*)d_in[1];
    const int* is_dna  = (const int*)d_in[2];
    const int* is_rna  = (const int*)d_in[3];
    const int* cmask   = (const int*)d_in[4];
    float* out = (float*)d_out;
    float* ws  = (float*)d_ws;

    const int b = in_sizes[2] / N;

    dim3 grid(NTRI, 1, b);   // 1088 x b = 2176 blocks -> 8.5 blocks/CU
    lddt_main_kernel<<<grid, BLOCK, 0, stream>>>(pred, truec, is_dna, is_rna, cmask, ws);
    finalize_kernel<<<1, BLOCK, 0, stream>>>(ws, out, b);
}

// Round 11
// 82.586 us; speedup vs baseline: 1.0724x; 1.0305x over previous
//
#include <hip/hip_runtime.h>
#include <math.h>

#define N      4096
#define BLOCK  256
#define JW     32                 // k-offsets per block
#define KSEG   (2048 / JW)        // 64 k-segments
#define NIT    (N / BLOCK)        // 16 i-tiles
#define NBLK   (NIT * KSEG)       // 1024 blocks per batch
#define WIN    (BLOCK + JW)       // 288-entry shared j-window

// Coordinates pre-scaled by L = log2(e) so e^dd == exp2(dd_scaled)  [R10-verified]
#define LOG2E   1.4426950408889634f
#define BASE_SQ 468.30802f        // 225 * L^2  (15^2 in scaled-d2 domain)
#define NUC_SQ  1404.92406f       // 675 * L^2  (30^2-15^2, scaled)
#define CLAMP_S 7.2134752f        // 5 * L
#define TPOIS   1.0e8f            // cm_j==0 poison: d2t ~ 1e16 -> never < cutoff

// s(e) = sum_k 1/(1+c_k e) = Pn(e)/Pd(e), c_k = e^{-t_k}, t = {.5,1,2,4}
#define PN0 4.0f
#define PN1 3.384183069f
#define PN2 0.750655861f
#define PN3 0.036699475f
#define PD1 1.128061023f
#define PD2 0.375327930f
#define PD3 0.036699475f
#define PD4 0.000553084f

// R4/R5: no fused atomic+ticket finalize (serialized wave-0s, +55us).
// R4: launch_bounds(256,8) -> 32-VGPR cap -> spills on fat bodies; keep (,4).
// R7/R10: issue-count cuts (pk f32, pk f16) are neutral - kernel is
// scheduler/efficiency-bound, not issue-bound. R2's simple scalar body ran
// at 2.5 cyc/pair vs 3.8 for all fused-triangle variants -> R11 recreates
// R2 efficiency on half the work via the circulant-offset decomposition:
// ordered sum = sum_i [ 2*sum_{k=1..2047} f(i,i+k) + f(i,i+2048) ].
// Every block identical (no tri decode/diag predicate/imbalance).
__global__ __launch_bounds__(BLOCK, 4) void lddt_main_kernel(
    const float* __restrict__ pred, const float* __restrict__ truec,
    const int* __restrict__ is_dna, const int* __restrict__ is_rna,
    const int* __restrict__ cmask, float* __restrict__ ws)
{
    const int kseg  = blockIdx.x;            // 0..63
    const int itile = blockIdx.y;            // 0..15
    const int batch = blockIdx.z;
    const int tid   = threadIdx.x;
    const int i     = itile * BLOCK + tid;
    const int kbase = kseg * JW;
    const bool lastseg = (kseg == KSEG - 1); // contains k == 2048

    const float* pb = pred  + (size_t)batch * N * 3;
    const float* tb = truec + (size_t)batch * N * 3;
    const int* dnab = is_dna + (size_t)batch * N;
    const int* rnab = is_rna + (size_t)batch * N;
    const int* cmb  = cmask  + (size_t)batch * N;

    // SoA j-window: j = (i0 + kbase + 1 + s) mod N for s in [0, WIN)
    __shared__ float spx[WIN], spy[WIN], spz[WIN];
    __shared__ float stx[WIN], sty[WIN], stz[WIN];
    __shared__ float snw[WIN];
    const int w0 = itile * BLOCK + kbase + 1;
    for (int s = tid; s < WIN; s += BLOCK) {
        const int j = (w0 + s) & (N - 1);
        spx[s] = pb[j*3+0] * LOG2E;
        spy[s] = pb[j*3+1] * LOG2E;
        spz[s] = pb[j*3+2] * LOG2E;
        const bool jc = cmb[j] != 0;
        stx[s] = jc ? tb[j*3+0] * LOG2E : TPOIS;   // poison -> m=0 via cutoff
        sty[s] = jc ? tb[j*3+1] * LOG2E : 0.0f;
        stz[s] = jc ? tb[j*3+2] * LOG2E : 0.0f;
        snw[s] = (dnab[j] | rnab[j]) ? NUC_SQ : 0.0f;
    }
    __syncthreads();

    const float pix = pb[i*3+0] * LOG2E, piy = pb[i*3+1] * LOG2E, piz = pb[i*3+2] * LOG2E;
    const float tix = tb[i*3+0] * LOG2E, tiy = tb[i*3+1] * LOG2E, tiz = tb[i*3+2] * LOG2E;
    const float inuc01 = (dnab[i] | rnab[i]) ? 1.0f : 0.0f;
    const float icm    = cmb[i] ? 1.0f : 0.0f;

    float num = 0.0f, den = 0.0f;

#pragma unroll 8
    for (int jj = 0; jj < JW; ++jj) {
        const int x = tid + jj;              // stride-1 lanes: conflict-free
        float dxp = pix - spx[x], dyp = piy - spy[x], dzp = piz - spz[x];
        float d2p = fmaf(dxp, dxp, fmaf(dyp, dyp, dzp * dzp));
        float dp  = __builtin_amdgcn_sqrtf(d2p);
        float dxt = tix - stx[x], dyt = tiy - sty[x], dzt = tiz - stz[x];
        float d2t = fmaf(dxt, dxt, fmaf(dyt, dyt, dzt * dzt));
        float dt  = __builtin_amdgcn_sqrtf(d2t);
        float dd  = fminf(fabsf(dt - dp), CLAMP_S);
        float e   = __builtin_amdgcn_exp2f(dd);
        float NNp = fmaf(e, fmaf(e, fmaf(e, PN3, PN2), PN1), PN0);
        float NDp = fmaf(e, fmaf(e, fmaf(e, fmaf(e, PD4, PD3), PD2), PD1), 1.0f);
        float cut = fmaf(inuc01, snw[x], BASE_SQ);
        float m   = (d2t < cut) ? 2.0f : 0.0f;      // symmetry weight folded
        if (lastseg && jj == JW - 1) m *= 0.5f;     // k==2048: weight 1
        den += m;
        num = fmaf(m * NNp, __builtin_amdgcn_rcpf(NDp), num);
    }

    num *= 0.25f * icm;   // threshold mean; cm_i gate
    den *= icm;

    for (int off = 32; off > 0; off >>= 1) {
        num += __shfl_down(num, off);
        den += __shfl_down(den, off);
    }
    __shared__ float rn[BLOCK / 64], rd[BLOCK / 64];
    const int wid = tid >> 6, lane = tid & 63;
    if (lane == 0) { rn[wid] = num; rd[wid] = den; }
    __syncthreads();
    if (tid == 0) {
        float tn = rn[0] + rn[1] + rn[2] + rn[3];
        float td = rd[0] + rd[1] + rd[2] + rd[3];
        const int bid = batch * NBLK + itile * KSEG + kseg;
        ws[bid * 2 + 0] = tn;   // plain stores to distinct slots
        ws[bid * 2 + 1] = td;
    }
}

__global__ __launch_bounds__(BLOCK) void finalize_kernel(
    const float* __restrict__ ws, float* __restrict__ out, int b)
{
    __shared__ float sn[4], sd[4];
    float acc = 0.0f;
    for (int k = 0; k < b; ++k) {
        float n = 0.0f, d = 0.0f;
        for (int p = threadIdx.x; p < NBLK; p += BLOCK) {
            n += ws[(k * NBLK + p) * 2 + 0];
            d += ws[(k * NBLK + p) * 2 + 1];
        }
        for (int off = 32; off > 0; off >>= 1) {
            n += __shfl_down(n, off);
            d += __shfl_down(d, off);
        }
        if ((threadIdx.x & 63) == 0) { sn[threadIdx.x >> 6] = n; sd[threadIdx.x >> 6] = d; }
        __syncthreads();
        if (threadIdx.x == 0) {
            float tn = sn[0] + sn[1] + sn[2] + sn[3];
            float td = sd[0] + sd[1] + sd[2] + sd[3];
            acc += tn / fmaxf(td, 1.0f);
        }
        __syncthreads();
    }
    if (threadIdx.x == 0) out[0] = 1.0f - acc / (float)b;
}

extern "C" void kernel_launch(void* const* d_in, const int* in_sizes, int n_in,
                              void* d_out, int out_size, void* d_ws, size_t ws_size,
                              hipStream_t stream) {
    const float* pred  = (const float*)d_in[0];
    const float* truec = (const float*)d_in[1];
    const int* is_dna  = (const int*)d_in[2];
    const int* is_rna  = (const int*)d_in[3];
    const int* cmask   = (const int*)d_in[4];
    float* out = (float*)d_out;
    float* ws  = (float*)d_ws;

    const int b = in_sizes[2] / N;

    dim3 grid(KSEG, NIT, b);   // 64 x 16 x b = 2048 identical blocks -> 8/CU
    lddt_main_kernel<<<grid, BLOCK, 0, stream>>>(pred, truec, is_dna, is_rna, cmask, ws);
    finalize_kernel<<<1, BLOCK, 0, stream>>>(ws, out, b);
}